// Round 5
// baseline (48.254 us; speedup 1.0000x reference)
//
#include <hip/hip_runtime.h>
#include <math.h>

#define WAVES_PER_BLOCK 4
#define THREADS (WAVES_PER_BLOCK * 64)
#define SEGS_PER_WAVE 2
#define MAX_V4 3   // 3 float4 per lane * 64 lanes = 768 vectorized elems per segment

typedef float f32x4 __attribute__((ext_vector_type(4)));

__device__ __forceinline__ void seg_generic(const float* __restrict__ logits,
                                            float* __restrict__ out,
                                            int start, int end, int lane) {
    float s = 0.f;
    for (int i = start + lane; i < end; i += 64)
        s += __expf(logits[i]);
    #pragma unroll
    for (int off = 32; off > 0; off >>= 1)
        s += __shfl_xor(s, off, 64);
    const float lg = __logf(s);
    for (int i = start + lane; i < end; i += 64)
        out[i] = logits[i] - lg;
}

__global__ __launch_bounds__(THREADS)
void jls_kernel(const float* __restrict__ logits,
                const int* __restrict__ prefix,
                float* __restrict__ out, int nseg) {
    const int wave = threadIdx.x >> 6;
    const int lane = threadIdx.x & 63;
    const int seg0 = (blockIdx.x * WAVES_PER_BLOCK + wave) * SEGS_PER_WAVE;
    if (seg0 >= nseg) return;
    const bool has1 = (seg0 + 1) < nseg;

    const int pA = (seg0 == 0) ? 0 : prefix[seg0 - 1];
    const int pB = prefix[seg0];
    const int pC = has1 ? prefix[seg0 + 1] : pB;

    // --- segment A geometry: [pA, pB) ---
    int a0A = (pA + 3) & ~3; if (a0A > pB) a0A = pB;
    const int headA = a0A - pA;
    const int nvA   = (pB - a0A) >> 2;
    const int tsA   = a0A + (nvA << 2);
    const int tailA = pB - tsA;

    // --- segment B geometry: [pB, pC) ---
    int a0B = (pB + 3) & ~3; if (a0B > pC) a0B = pC;
    const int headB = a0B - pB;
    const int nvB   = (pC - a0B) >> 2;
    const int tsB   = a0B + (nvB << 2);
    const int tailB = pC - tsB;

    if (nvA <= 64 * MAX_V4 && nvB <= 64 * MAX_V4) {
        // ---- fast path: both segments in registers, chains interleaved ----
        float hvA = 0.f, tvA = 0.f, hvB = 0.f, tvB = 0.f;
        f32x4 vA[MAX_V4], vB[MAX_V4];
        bool okA[MAX_V4], okB[MAX_V4];

        // issue all loads first (maximize MLP)
        if (lane < headA) hvA = logits[pA + lane];
        if (lane < headB) hvB = logits[pB + lane];
        #pragma unroll
        for (int k = 0; k < MAX_V4; ++k) {
            const int vi = lane + k * 64;
            okA[k] = vi < nvA;
            if (okA[k]) vA[k] = *reinterpret_cast<const f32x4*>(logits + a0A + (vi << 2));
            okB[k] = vi < nvB;
            if (okB[k]) vB[k] = *reinterpret_cast<const f32x4*>(logits + a0B + (vi << 2));
        }
        if (lane < tailA) tvA = logits[tsA + lane];
        if (lane < tailB) tvB = logits[tsB + lane];

        // partial sums
        float sA = (lane < headA) ? __expf(hvA) : 0.f;
        float sB = (lane < headB) ? __expf(hvB) : 0.f;
        #pragma unroll
        for (int k = 0; k < MAX_V4; ++k) {
            if (okA[k]) sA += __expf(vA[k].x) + __expf(vA[k].y) + __expf(vA[k].z) + __expf(vA[k].w);
            if (okB[k]) sB += __expf(vB[k].x) + __expf(vB[k].y) + __expf(vB[k].z) + __expf(vB[k].w);
        }
        if (lane < tailA) sA += __expf(tvA);
        if (lane < tailB) sB += __expf(tvB);

        // two independent butterflies, interleaved
        #pragma unroll
        for (int off = 32; off > 0; off >>= 1) {
            sA += __shfl_xor(sA, off, 64);
            sB += __shfl_xor(sB, off, 64);
        }
        const float lgA = __logf(sA);
        const float lgB = __logf(sB);

        // stores (vector part non-temporal: output is never re-read)
        if (lane < headA) out[pA + lane] = hvA - lgA;
        if (lane < headB) out[pB + lane] = hvB - lgB;
        #pragma unroll
        for (int k = 0; k < MAX_V4; ++k) {
            const int vi = lane + k * 64;
            if (okA[k]) {
                f32x4 r = vA[k] - lgA;
                __builtin_nontemporal_store(r, reinterpret_cast<f32x4*>(out + a0A + (vi << 2)));
            }
            if (okB[k]) {
                f32x4 r = vB[k] - lgB;
                __builtin_nontemporal_store(r, reinterpret_cast<f32x4*>(out + a0B + (vi << 2)));
            }
        }
        if (lane < tailA) out[tsA + lane] = tvA - lgA;
        if (lane < tailB) out[tsB + lane] = tvB - lgB;
    } else {
        // ---- generic fallback (not taken for this data distribution) ----
        seg_generic(logits, out, pA, pB, lane);
        if (has1) seg_generic(logits, out, pB, pC, lane);
    }
}

extern "C" void kernel_launch(void* const* d_in, const int* in_sizes, int n_in,
                              void* d_out, int out_size, void* d_ws, size_t ws_size,
                              hipStream_t stream) {
    const float* logits = (const float*)d_in[0];
    const int* prefix = (const int*)d_in[1];
    float* out = (float*)d_out;
    const int nseg = in_sizes[1];

    const int segs_per_block = WAVES_PER_BLOCK * SEGS_PER_WAVE;
    const int blocks = (nseg + segs_per_block - 1) / segs_per_block;
    jls_kernel<<<blocks, THREADS, 0, stream>>>(logits, prefix, out, nseg);
}

// Round 6
// 48.082 us; speedup vs baseline: 1.0036x; 1.0036x over previous
//
#include <hip/hip_runtime.h>
#include <math.h>

#define WPB 4
#define THREADS (WPB * 64)
#define MAX_V4 3          // 3 float4/lane * 64 lanes = 768 vector elems per segment
#define NBLOCKS 2048      // persistent grid: 8192 waves, 8 segments each at nseg=65536

typedef float f32x4 __attribute__((ext_vector_type(4)));

struct Seg {
    int start, end, a0, nv, ts, head, tail;
    float hv, tv;
    f32x4 v0, v1, v2;
};

__device__ __forceinline__ void seg_generic(const float* __restrict__ logits,
                                            float* __restrict__ out,
                                            int start, int end, int lane) {
    float s = 0.f;
    for (int i = start + lane; i < end; i += 64)
        s += __expf(logits[i]);
    #pragma unroll
    for (int off = 32; off > 0; off >>= 1)
        s += __shfl_xor(s, off, 64);
    const float lg = __logf(s);
    for (int i = start + lane; i < end; i += 64)
        out[i] = logits[i] - lg;
}

// compute geometry and ISSUE all global loads for one segment (no consume)
__device__ __forceinline__ void issue_data(Seg& S, int start, int end,
                                           const float* __restrict__ logits, int lane) {
    S.start = start; S.end = end;
    int a0 = (start + 3) & ~3; if (a0 > end) a0 = end;
    S.a0 = a0;
    S.head = a0 - start;
    const int nv = (end - a0) >> 2;
    S.nv = nv;
    S.ts = a0 + (nv << 2);
    S.tail = end - S.ts;
    S.hv = 0.f; S.tv = 0.f;
    S.v0 = 0.f; S.v1 = 0.f; S.v2 = 0.f;
    if (nv > 64 * MAX_V4) return;            // generic fallback path (never for this data)
    if (lane < S.head) S.hv = logits[start + lane];
    if (lane       < nv) S.v0 = *reinterpret_cast<const f32x4*>(logits + a0 + (lane << 2));
    if (lane + 64  < nv) S.v1 = *reinterpret_cast<const f32x4*>(logits + a0 + ((lane + 64) << 2));
    if (lane + 128 < nv) S.v2 = *reinterpret_cast<const f32x4*>(logits + a0 + ((lane + 128) << 2));
    if (lane < S.tail) S.tv = logits[S.ts + lane];
}

// consume: exp, wave-reduce, log, write out
__device__ __forceinline__ void finish(const Seg& S, const float* __restrict__ logits,
                                       float* __restrict__ out, int lane) {
    if (S.nv > 64 * MAX_V4) { seg_generic(logits, out, S.start, S.end, lane); return; }
    const bool ok0 = lane < S.nv, ok1 = lane + 64 < S.nv, ok2 = lane + 128 < S.nv;
    float s = (lane < S.head) ? __expf(S.hv) : 0.f;
    if (ok0) s += __expf(S.v0.x) + __expf(S.v0.y) + __expf(S.v0.z) + __expf(S.v0.w);
    if (ok1) s += __expf(S.v1.x) + __expf(S.v1.y) + __expf(S.v1.z) + __expf(S.v1.w);
    if (ok2) s += __expf(S.v2.x) + __expf(S.v2.y) + __expf(S.v2.z) + __expf(S.v2.w);
    if (lane < S.tail) s += __expf(S.tv);
    #pragma unroll
    for (int off = 32; off > 0; off >>= 1)
        s += __shfl_xor(s, off, 64);
    const float lg = __logf(s);
    if (lane < S.head) out[S.start + lane] = S.hv - lg;
    if (ok0) { f32x4 r = S.v0 - lg;
        __builtin_nontemporal_store(r, reinterpret_cast<f32x4*>(out + S.a0 + (lane << 2))); }
    if (ok1) { f32x4 r = S.v1 - lg;
        __builtin_nontemporal_store(r, reinterpret_cast<f32x4*>(out + S.a0 + ((lane + 64) << 2))); }
    if (ok2) { f32x4 r = S.v2 - lg;
        __builtin_nontemporal_store(r, reinterpret_cast<f32x4*>(out + S.a0 + ((lane + 128) << 2))); }
    if (lane < S.tail) out[S.ts + lane] = S.tv - lg;
}

__global__ __launch_bounds__(THREADS)
void jls_kernel(const float* __restrict__ logits,
                const int* __restrict__ prefix,
                float* __restrict__ out, int nseg) {
    const int wave = threadIdx.x >> 6;
    const int lane = threadIdx.x & 63;
    const int w = blockIdx.x * WPB + wave;
    const int stride = gridDim.x * WPB;
    if (w >= nseg) return;
    const int nIter = (nseg - w + stride - 1) / stride;
    const bool pf_ok = (nIter <= 64);

    // lane-parallel prefix prefetch: lane k holds bounds of this wave's k-th segment
    int pvS = 0, pvE = 0;
    if (pf_ok && lane < nIter) {
        const int sk = w + lane * stride;
        pvS = (sk == 0) ? 0 : prefix[sk - 1];
        pvE = prefix[sk];
    }

    auto bounds = [&](int k, int& s0, int& s1) {
        if (pf_ok) { s0 = __shfl(pvS, k, 64); s1 = __shfl(pvE, k, 64); }
        else { const int sk = w + k * stride; s0 = (sk == 0) ? 0 : prefix[sk - 1]; s1 = prefix[sk]; }
    };

    Seg A, B;
    int it = 0;
    { int s0, s1; bounds(0, s0, s1); issue_data(A, s0, s1, logits, lane); }
    while (true) {
        const bool hb = (it + 1) < nIter;
        if (hb) { int s0, s1; bounds(it + 1, s0, s1); issue_data(B, s0, s1, logits, lane); }
        finish(A, logits, out, lane);
        if (!hb) break;
        ++it;
        const bool hc = (it + 1) < nIter;
        if (hc) { int s0, s1; bounds(it + 1, s0, s1); issue_data(A, s0, s1, logits, lane); }
        finish(B, logits, out, lane);
        if (!hc) break;
        ++it;
    }
}

extern "C" void kernel_launch(void* const* d_in, const int* in_sizes, int n_in,
                              void* d_out, int out_size, void* d_ws, size_t ws_size,
                              hipStream_t stream) {
    const float* logits = (const float*)d_in[0];
    const int* prefix = (const int*)d_in[1];
    float* out = (float*)d_out;
    const int nseg = in_sizes[1];

    int blocks = (nseg + WPB - 1) / WPB;
    if (blocks > NBLOCKS) blocks = NBLOCKS;
    jls_kernel<<<blocks, THREADS, 0, stream>>>(logits, prefix, out, nseg);
}

// Round 7
// 45.628 us; speedup vs baseline: 1.0576x; 1.0538x over previous
//
#include <hip/hip_runtime.h>
#include <math.h>

#define WAVES_PER_BLOCK 4
#define THREADS (WAVES_PER_BLOCK * 64)
#define MAX_V4 3   // 3 float4 per lane * 64 lanes = 768 vectorized elems per segment

typedef float f32x4 __attribute__((ext_vector_type(4)));

__global__ __launch_bounds__(THREADS)
void jls_kernel(const float* __restrict__ logits,
                const int* __restrict__ prefix,
                float* __restrict__ out, int nseg) {
    const int wave = threadIdx.x >> 6;
    const int lane = threadIdx.x & 63;
    const int seg = blockIdx.x * WAVES_PER_BLOCK + wave;
    if (seg >= nseg) return;

    const int start = (seg == 0) ? 0 : prefix[seg - 1];
    const int end   = prefix[seg];
    if (end <= start) return;

    // 16B-aligned vectorized middle region, scalar head/tail
    int a0 = (start + 3) & ~3; if (a0 > end) a0 = end;
    const int head = a0 - start;              // 0..3
    const int nv   = (end - a0) >> 2;         // number of float4
    const int tail_start = a0 + (nv << 2);
    const int tail = end - tail_start;        // 0..3

    if (nv > 0 && nv <= 64 * MAX_V4) {
        // ---- fast path: branchless clamped loads, whole segment in registers ----
        const float* __restrict__ vbase = logits + a0;

        int i0 = lane;            if (i0 > nv - 1) i0 = nv - 1;
        int i1 = lane + 64;       if (i1 > nv - 1) i1 = nv - 1;
        int i2 = lane + 128;      if (i2 > nv - 1) i2 = nv - 1;
        const bool ok0 = lane       < nv;
        const bool ok1 = lane + 64  < nv;
        const bool ok2 = lane + 128 < nv;

        // unconditional vector loads (clamped addresses are always in-bounds)
        f32x4 v0 = *reinterpret_cast<const f32x4*>(vbase + (i0 << 2));
        f32x4 v1 = *reinterpret_cast<const f32x4*>(vbase + (i1 << 2));
        f32x4 v2 = *reinterpret_cast<const f32x4*>(vbase + (i2 << 2));
        float hv = 0.f, tv = 0.f;
        if (lane < head) hv = logits[start + lane];
        if (lane < tail) tv = logits[tail_start + lane];

        float s = 0.f;
        {
            float e0 = __expf(v0.x) + __expf(v0.y) + __expf(v0.z) + __expf(v0.w);
            float e1 = __expf(v1.x) + __expf(v1.y) + __expf(v1.z) + __expf(v1.w);
            float e2 = __expf(v2.x) + __expf(v2.y) + __expf(v2.z) + __expf(v2.w);
            s += ok0 ? e0 : 0.f;
            s += ok1 ? e1 : 0.f;
            s += ok2 ? e2 : 0.f;
        }
        if (lane < head) s += __expf(hv);
        if (lane < tail) s += __expf(tv);

        #pragma unroll
        for (int off = 32; off > 0; off >>= 1)
            s += __shfl_xor(s, off, 64);
        const float lg = __logf(s);

        if (lane < head) out[start + lane] = hv - lg;
        if (ok0) { f32x4 r = v0 - lg; *reinterpret_cast<f32x4*>(out + a0 + (lane << 2)) = r; }
        if (ok1) { f32x4 r = v1 - lg; *reinterpret_cast<f32x4*>(out + a0 + ((lane + 64) << 2)) = r; }
        if (ok2) { f32x4 r = v2 - lg; *reinterpret_cast<f32x4*>(out + a0 + ((lane + 128) << 2)) = r; }
        if (lane < tail) out[tail_start + lane] = tv - lg;
    } else {
        // ---- generic fallback (not taken for this data distribution) ----
        float s = 0.f;
        for (int i = start + lane; i < end; i += 64)
            s += __expf(logits[i]);
        #pragma unroll
        for (int off = 32; off > 0; off >>= 1)
            s += __shfl_xor(s, off, 64);
        const float lg = __logf(s);
        for (int i = start + lane; i < end; i += 64)
            out[i] = logits[i] - lg;
    }
}

extern "C" void kernel_launch(void* const* d_in, const int* in_sizes, int n_in,
                              void* d_out, int out_size, void* d_ws, size_t ws_size,
                              hipStream_t stream) {
    const float* logits = (const float*)d_in[0];
    const int* prefix = (const int*)d_in[1];
    float* out = (float*)d_out;
    const int nseg = in_sizes[1];

    const int blocks = (nseg + WAVES_PER_BLOCK - 1) / WAVES_PER_BLOCK;
    jls_kernel<<<blocks, THREADS, 0, stream>>>(logits, prefix, out, nseg);
}

// Round 8
// 45.314 us; speedup vs baseline: 1.0649x; 1.0069x over previous
//
#include <hip/hip_runtime.h>
#include <math.h>

#define WAVES_PER_BLOCK 4
#define THREADS (WAVES_PER_BLOCK * 64)
#define MAX_V4 3   // 3 float4 per lane * 64 lanes = 768 vectorized elems per segment

typedef float f32x4 __attribute__((ext_vector_type(4)));

__global__ __launch_bounds__(THREADS)
void jls_kernel(const float* __restrict__ logits,
                const int* __restrict__ prefix,
                float* __restrict__ out, int nseg) {
    const int wave = threadIdx.x >> 6;
    const int lane = threadIdx.x & 63;
    const int seg = blockIdx.x * WAVES_PER_BLOCK + wave;
    if (seg >= nseg) return;

    const int start = (seg == 0) ? 0 : prefix[seg - 1];
    const int end   = prefix[seg];
    if (end <= start) return;

    // 16B-aligned vectorized middle region, scalar head/tail
    int a0 = (start + 3) & ~3; if (a0 > end) a0 = end;
    const int head = a0 - start;              // 0..3
    const int nv   = (end - a0) >> 2;         // number of float4
    const int tail_start = a0 + (nv << 2);
    const int tail = end - tail_start;        // 0..3

    if (nv > 0 && nv <= 64 * MAX_V4) {
        // ---- fast path: fully branchless vector body ----
        const float* __restrict__ vbase = logits + a0;

        int i0 = lane;            if (i0 > nv - 1) i0 = nv - 1;
        int i1 = lane + 64;       if (i1 > nv - 1) i1 = nv - 1;
        int i2 = lane + 128;      if (i2 > nv - 1) i2 = nv - 1;
        const bool ok0 = lane       < nv;
        const bool ok1 = lane + 64  < nv;
        const bool ok2 = lane + 128 < nv;

        // unconditional clamped vector loads (always in-bounds)
        f32x4 v0 = *reinterpret_cast<const f32x4*>(vbase + (i0 << 2));
        f32x4 v1 = *reinterpret_cast<const f32x4*>(vbase + (i1 << 2));
        f32x4 v2 = *reinterpret_cast<const f32x4*>(vbase + (i2 << 2));
        float hv = 0.f, tv = 0.f;
        if (lane < head) hv = logits[start + lane];
        if (lane < tail) tv = logits[tail_start + lane];

        float s = 0.f;
        {
            float e0 = __expf(v0.x) + __expf(v0.y) + __expf(v0.z) + __expf(v0.w);
            float e1 = __expf(v1.x) + __expf(v1.y) + __expf(v1.z) + __expf(v1.w);
            float e2 = __expf(v2.x) + __expf(v2.y) + __expf(v2.z) + __expf(v2.w);
            s += ok0 ? e0 : 0.f;
            s += ok1 ? e1 : 0.f;
            s += ok2 ? e2 : 0.f;
        }
        if (lane < head) s += __expf(hv);
        if (lane < tail) s += __expf(tv);

        #pragma unroll
        for (int off = 32; off > 0; off >>= 1)
            s += __shfl_xor(s, off, 64);
        const float lg = __logf(s);

        // unconditional clamped stores: clamped lanes hold logits[nv-1], so
        // v - lg is the CORRECT value for the clamped address (dup write, same line)
        float* __restrict__ obase = out + a0;
        { f32x4 r = v0 - lg; *reinterpret_cast<f32x4*>(obase + (i0 << 2)) = r; }
        { f32x4 r = v1 - lg; *reinterpret_cast<f32x4*>(obase + (i1 << 2)) = r; }
        { f32x4 r = v2 - lg; *reinterpret_cast<f32x4*>(obase + (i2 << 2)) = r; }
        if (lane < head) out[start + lane] = hv - lg;
        if (lane < tail) out[tail_start + lane] = tv - lg;
    } else {
        // ---- generic fallback (not taken for this data distribution) ----
        float s = 0.f;
        for (int i = start + lane; i < end; i += 64)
            s += __expf(logits[i]);
        #pragma unroll
        for (int off = 32; off > 0; off >>= 1)
            s += __shfl_xor(s, off, 64);
        const float lg = __logf(s);
        for (int i = start + lane; i < end; i += 64)
            out[i] = logits[i] - lg;
    }
}

extern "C" void kernel_launch(void* const* d_in, const int* in_sizes, int n_in,
                              void* d_out, int out_size, void* d_ws, size_t ws_size,
                              hipStream_t stream) {
    const float* logits = (const float*)d_in[0];
    const int* prefix = (const int*)d_in[1];
    float* out = (float*)d_out;
    const int nseg = in_sizes[1];

    const int blocks = (nseg + WAVES_PER_BLOCK - 1) / WAVES_PER_BLOCK;
    jls_kernel<<<blocks, THREADS, 0, stream>>>(logits, prefix, out, nseg);
}